// Round 1
// baseline (187.756 us; speedup 1.0000x reference)
//
#include <hip/hip_runtime.h>

// SimCLR fused pipeline, round 10.
// Change vs r9: sim_mfma re-tiled from 64 rows/wave to 32 rows/wave.
//   r9's wave held a[4][4] (64 VGPR of A-frags) + dbuf B + acc + rs ->
//   combined VGPR+AGPR ~150-160 -> 129-256 occupancy bucket -> 2 waves/SIMD
//   (measured OccupancyPercent 24% = 7.7 waves/CU). Latency-bound: MfmaUtil 13%,
//   VALUBusy 18%. Halving the row tile puts the wave in the <=128 bucket
//   (__launch_bounds__(256,4) enforces) -> 4 waves/SIMD, grid 2048 blocks.
// Everything else (gemm1, gemm2, row_finalize, convert_w, psum layout) identical.

#define NB   4096
#define DIN  192
#define DHID 512
#define DOUT 128
#define N2   8192   // 2*NB
#define NSPLIT 32   // sim col-splits; 256 cols per block
#define SIM_ITERS 16

typedef short short8 __attribute__((ext_vector_type(8)));   // 8 bf16 (4 VGPRs)
typedef float floatx4 __attribute__((ext_vector_type(4)));  // MFMA C/D frag

__device__ inline float fast_exp2(float x) {
#if __has_builtin(__builtin_amdgcn_exp2f)
    return __builtin_amdgcn_exp2f(x);
#else
    return exp2f(x);
#endif
}

__device__ inline unsigned short bf16_rne(float x) {
    unsigned int u = __float_as_uint(x);
    return (unsigned short)((u + 0x7fffu + ((u >> 16) & 1u)) >> 16);
}

// ---------------- convert W1, W2 -> bf16 ------------------------------------
__global__ __launch_bounds__(256) void convert_w(
    const float* __restrict__ W1, const float* __restrict__ W2,
    unsigned short* __restrict__ W1b, unsigned short* __restrict__ W2b)
{
    const int NW1 = DHID * DIN / 4;   // 24576 float4
    const int NW2 = DOUT * DHID / 4;  // 16384 float4
    int id = blockIdx.x * 256 + threadIdx.x;
    const float* src; unsigned short* dst; int off;
    if (id < NW1)            { src = W1; dst = W1b; off = id; }
    else if (id < NW1 + NW2) { src = W2; dst = W2b; off = id - NW1; }
    else return;
    float4 x = ((const float4*)src)[off];
    unsigned int p0 = bf16_rne(x.x) | ((unsigned int)bf16_rne(x.y) << 16);
    unsigned int p1 = bf16_rne(x.z) | ((unsigned int)bf16_rne(x.w) << 16);
    ((uint2*)dst)[off] = make_uint2(p0, p1);
}

// ------- GEMM1 (bf16 MFMA): Y = [h1;h2] @ W1^T + b1, fused BN col-sums -----
// grid (64 m-blocks of 128 rows, 8 n-splits of 64 cols), 256 thr (4 waves).
// Wave: 32 rows (2 mt) x 64 cols (4 nt), K=192 (6 kc).
__global__ __launch_bounds__(256) void gemm1_mfma(
    const float* __restrict__ h1, const float* __restrict__ h2,
    const unsigned short* __restrict__ W1b, const float* __restrict__ b1,
    float* __restrict__ Y, float* __restrict__ psumc, float* __restrict__ psqc)
{
    const int t = threadIdx.x;
    const int wave = t >> 6, lane = t & 63;
    const int quad = lane >> 4, l15 = lane & 15;
    const int mb = blockIdx.x;
    const int m0 = mb * 128 + wave * 32;
    const int n0 = blockIdx.y * 64;
    const int v  = (mb >= 32);

    short8 a[2][6];
    #pragma unroll
    for (int mt = 0; mt < 2; ++mt) {
        int row = m0 + mt * 16 + l15;
        const float* hsrc = (row < NB) ? (h1 + (size_t)row * DIN)
                                       : (h2 + (size_t)(row - NB) * DIN);
        #pragma unroll
        for (int kc = 0; kc < 6; ++kc) {
            const float4* p = (const float4*)(hsrc + kc * 32 + quad * 8);
            float4 x0 = p[0], x1 = p[1];
            float xs[8] = {x0.x,x0.y,x0.z,x0.w,x1.x,x1.y,x1.z,x1.w};
            #pragma unroll
            for (int j = 0; j < 8; ++j) a[mt][kc][j] = (short)bf16_rne(xs[j]);
        }
    }

    #pragma unroll
    for (int nt = 0; nt < 4; ++nt) {
        const int col = n0 + nt * 16 + l15;
        const short8* bptr = (const short8*)(W1b + (size_t)col * DIN + quad * 8);
        short8 b[6];
        #pragma unroll
        for (int kc = 0; kc < 6; ++kc) b[kc] = bptr[kc * 4];
        floatx4 acc[2] = {{0.f,0.f,0.f,0.f},{0.f,0.f,0.f,0.f}};
        #pragma unroll
        for (int kc = 0; kc < 6; ++kc)
            #pragma unroll
            for (int mt = 0; mt < 2; ++mt)
                acc[mt] = __builtin_amdgcn_mfma_f32_16x16x32_bf16(a[mt][kc], b[kc], acc[mt], 0,0,0);
        const float bias = b1[col];
        float cs = 0.f, cq = 0.f;
        #pragma unroll
        for (int mt = 0; mt < 2; ++mt)
            #pragma unroll
            for (int reg = 0; reg < 4; ++reg) {
                float y = acc[mt][reg] + bias;
                int row = m0 + mt * 16 + quad * 4 + reg;
                Y[(size_t)row * DHID + col] = y;
                cs += y; cq += y * y;
            }
        cs += __shfl_xor(cs, 16); cs += __shfl_xor(cs, 32);
        cq += __shfl_xor(cq, 16); cq += __shfl_xor(cq, 32);
        if (quad == 0) {
            atomicAdd(psumc + v * DHID + col, cs);
            atomicAdd(psqc  + v * DHID + col, cq);
        }
    }
}

#define ZSCALE 1.6986436f   // sqrt(2*log2(e)); Zb = z*ZSCALE so dot = exp2 arg

// ---- GEMM2 (bf16 MFMA): z = relu(bn(Y)) @ W2^T + b2, L2-norm --------------
// Block: 16 rows x 128 cols, 4 waves (wave w = cols w*32..+31, 2 nt).
// bn-finalize fused in prologue (LDS). 4-wave sq combine via LDS.
// grid 512 x 256 thr.
__global__ __launch_bounds__(256) void gemm2_mfma(
    const float* __restrict__ Y, const unsigned short* __restrict__ W2b,
    const float* __restrict__ psumc, const float* __restrict__ psqc,
    const float* __restrict__ gamma, const float* __restrict__ beta,
    const float* __restrict__ b2,
    unsigned short* __restrict__ Zb, float* __restrict__ outz)
{
    __shared__ float sc_sh[DHID], sh_sh[DHID];
    __shared__ float sq_lds[4][16];
    const int t = threadIdx.x;
    const int wave = t >> 6, lane = t & 63;
    const int quad = lane >> 4, l15 = lane & 15;
    const int mtbase = blockIdx.x * 16;
    const int v = (mtbase >= NB);

    for (int c = t; c < DHID; c += 256) {
        float mean = psumc[v * DHID + c] * (1.0f / NB);
        float var  = psqc [v * DHID + c] * (1.0f / NB) - mean * mean;
        float rstd = rsqrtf(var + 1e-5f);
        float scv = gamma[c] * rstd;
        sc_sh[c] = scv;
        sh_sh[c] = beta[c] - mean * scv;
    }
    __syncthreads();

    const float* yrow = Y + (size_t)(mtbase + l15) * DHID;
    floatx4 acc[2] = {{0.f,0.f,0.f,0.f},{0.f,0.f,0.f,0.f}};
    for (int kc = 0; kc < 16; ++kc) {
        const int k = kc * 32 + quad * 8;
        float4 y0 = *(const float4*)(yrow + k);
        float4 y1 = *(const float4*)(yrow + k + 4);
        float4 s0 = *(const float4*)&sc_sh[k], s1 = *(const float4*)&sc_sh[k + 4];
        float4 h0 = *(const float4*)&sh_sh[k], h1v = *(const float4*)&sh_sh[k + 4];
        float xs[8];
        xs[0] = fmaxf(y0.x * s0.x + h0.x, 0.f);
        xs[1] = fmaxf(y0.y * s0.y + h0.y, 0.f);
        xs[2] = fmaxf(y0.z * s0.z + h0.z, 0.f);
        xs[3] = fmaxf(y0.w * s0.w + h0.w, 0.f);
        xs[4] = fmaxf(y1.x * s1.x + h1v.x, 0.f);
        xs[5] = fmaxf(y1.y * s1.y + h1v.y, 0.f);
        xs[6] = fmaxf(y1.z * s1.z + h1v.z, 0.f);
        xs[7] = fmaxf(y1.w * s1.w + h1v.w, 0.f);
        short8 a;
        #pragma unroll
        for (int j = 0; j < 8; ++j) a[j] = (short)bf16_rne(xs[j]);
        #pragma unroll
        for (int nt = 0; nt < 2; ++nt) {
            const int col = wave * 32 + nt * 16 + l15;
            short8 b = *(const short8*)(W2b + (size_t)col * DHID + k);
            acc[nt] = __builtin_amdgcn_mfma_f32_16x16x32_bf16(a, b, acc[nt], 0,0,0);
        }
    }
    float bias[2];
    #pragma unroll
    for (int nt = 0; nt < 2; ++nt) bias[nt] = b2[wave * 32 + nt * 16 + l15];

    float zv[4][2];
    #pragma unroll
    for (int reg = 0; reg < 4; ++reg) {
        float sq = 0.f;
        #pragma unroll
        for (int nt = 0; nt < 2; ++nt) {
            zv[reg][nt] = acc[nt][reg] + bias[nt];
            sq += zv[reg][nt] * zv[reg][nt];
        }
        sq += __shfl_xor(sq, 1); sq += __shfl_xor(sq, 2);
        sq += __shfl_xor(sq, 4); sq += __shfl_xor(sq, 8);
        if (l15 == 0) sq_lds[wave][quad * 4 + reg] = sq;
    }
    __syncthreads();
    #pragma unroll
    for (int reg = 0; reg < 4; ++reg) {
        float tot = sq_lds[0][quad * 4 + reg] + sq_lds[1][quad * 4 + reg]
                  + sq_lds[2][quad * 4 + reg] + sq_lds[3][quad * 4 + reg];
        float inv = 1.0f / fmaxf(sqrtf(tot), 1e-12f);
        const int row = mtbase + quad * 4 + reg;
        const size_t ob = (size_t)row * DOUT;
        #pragma unroll
        for (int nt = 0; nt < 2; ++nt) {
            const int col = wave * 32 + nt * 16 + l15;
            float z = zv[reg][nt] * inv;
            outz[ob + col] = z;
            Zb[ob + col] = bf16_rne(z * ZSCALE);
        }
    }
}

// ---- sim: psum_row = sum_cols exp2(Zb . Zb^T)  (diag included; subtracted
// in row_finalize). Round-10 tiling: wave owns 32 rows (2 A-tiles, 32 VGPR)
// so combined reg use fits the <=128 occupancy bucket -> 4 waves/SIMD
// (r9's 64-row wave was in the 129-256 bucket -> 2 waves/SIMD, Occ 24%).
// Dynamic loop, dist-1 double-buffered 16-col B-tile; 8 MFMA + 8 exp per iter.
// grid (64, NSPLIT) x 256 thr.
__global__ __launch_bounds__(256, 4) void sim_mfma(
    const unsigned short* __restrict__ Zb, float* __restrict__ psum)
{
    const int t = threadIdx.x;
    const int wave = t >> 6, lane = t & 63;
    const int quad = lane >> 4, l15 = lane & 15;
    const int mbase = blockIdx.x * 128 + wave * 32;   // 32 rows per wave
    const int cs = blockIdx.y;                        // 0..NSPLIT-1
    const int cbase = cs * (N2 / NSPLIT);             // 256-col slice

    short8 a[2][4];
    #pragma unroll
    for (int at = 0; at < 2; ++at) {
        const short8* zra = (const short8*)(Zb + (size_t)(mbase + at * 16 + l15) * DOUT + quad * 8);
        #pragma unroll
        for (int kc = 0; kc < 4; ++kc) a[at][kc] = zra[kc * 4];
    }

    float rs[2][4];
    #pragma unroll
    for (int at = 0; at < 2; ++at)
        #pragma unroll
        for (int r = 0; r < 4; ++r) rs[at][r] = 0.f;

    short8 bcur[4], bnext[4];
    {
        const short8* zb = (const short8*)(Zb + (size_t)(cbase + l15) * DOUT + quad * 8);
        #pragma unroll
        for (int kc = 0; kc < 4; ++kc) bcur[kc] = zb[kc * 4];
    }

    for (int nt = 0; nt < SIM_ITERS; ++nt) {
        const int cn = cbase + ((nt + 1) & (SIM_ITERS - 1)) * 16;
        const short8* zbn = (const short8*)(Zb + (size_t)(cn + l15) * DOUT + quad * 8);
        #pragma unroll
        for (int kc = 0; kc < 4; ++kc) bnext[kc] = zbn[kc * 4];

        floatx4 acc[2] = {{0.f,0.f,0.f,0.f},{0.f,0.f,0.f,0.f}};
        #pragma unroll
        for (int kc = 0; kc < 4; ++kc)
            #pragma unroll
            for (int at = 0; at < 2; ++at)
                acc[at] = __builtin_amdgcn_mfma_f32_16x16x32_bf16(a[at][kc], bcur[kc], acc[at], 0, 0, 0);

        #pragma unroll
        for (int at = 0; at < 2; ++at)
            #pragma unroll
            for (int r = 0; r < 4; ++r)
                rs[at][r] += fast_exp2(acc[at][r]);

        #pragma unroll
        for (int kc = 0; kc < 4; ++kc) bcur[kc] = bnext[kc];
    }

    #pragma unroll
    for (int at = 0; at < 2; ++at) {
        const int gi0 = mbase + at * 16 + quad * 4;
        #pragma unroll
        for (int r = 0; r < 4; ++r) {
            float s = rs[at][r];
            s += __shfl_xor(s, 1);
            s += __shfl_xor(s, 2);
            s += __shfl_xor(s, 4);
            s += __shfl_xor(s, 8);
            if (l15 == 0) psum[(size_t)cs * N2 + gi0 + r] = s;
        }
    }
}

// ---- per-row lse - pos, minus diag term; block-reduce -> atomic loss ------
__global__ __launch_bounds__(256) void row_finalize(
    const unsigned short* __restrict__ Zb, const float* __restrict__ psum,
    float* __restrict__ out)
{
    int i = blockIdx.x * 256 + threadIdx.x;
    float s = 0.f;
    #pragma unroll
    for (int cs = 0; cs < NSPLIT; ++cs) s += psum[(size_t)cs * N2 + i];
    int k = i & (NB - 1);
    const uint4* z1 = (const uint4*)(Zb + (size_t)k * DOUT);
    const uint4* z2 = (const uint4*)(Zb + (size_t)(k + NB) * DOUT);
    float d12 = 0.f, d11 = 0.f, d22 = 0.f;
    #pragma unroll
    for (int q = 0; q < 16; ++q) {
        uint4 a = z1[q], bqq = z2[q];
        const unsigned int aw[4] = {a.x, a.y, a.z, a.w};
        const unsigned int bw[4] = {bqq.x, bqq.y, bqq.z, bqq.w};
        #pragma unroll
        for (int c = 0; c < 4; ++c) {
            float alo = __uint_as_float(aw[c] << 16);
            float ahi = __uint_as_float(aw[c] & 0xffff0000u);
            float blo = __uint_as_float(bw[c] << 16);
            float bhi = __uint_as_float(bw[c] & 0xffff0000u);
            d12 += alo * blo + ahi * bhi;
            d11 += alo * alo + ahi * ahi;
            d22 += blo * blo + bhi * bhi;
        }
    }
    float dself = (i < NB) ? d11 : d22;
    // Zb is scaled: dot' = 2*log2(e)*dot => 2*dot = dot'*ln2; diag = exp2(dot')
    float rowval = logf(s - fast_exp2(dself)) - d12 * 0.69314718f;

    float r = rowval;
    r += __shfl_xor(r, 1);  r += __shfl_xor(r, 2);  r += __shfl_xor(r, 4);
    r += __shfl_xor(r, 8);  r += __shfl_xor(r, 16); r += __shfl_xor(r, 32);
    __shared__ float wsr[4];
    int lane = threadIdx.x & 63, w = threadIdx.x >> 6;
    if (lane == 0) wsr[w] = r;
    __syncthreads();
    if (threadIdx.x == 0)
        atomicAdd(out, (wsr[0] + wsr[1] + wsr[2] + wsr[3]) * (1.0f / N2));
}

extern "C" void kernel_launch(void* const* d_in, const int* in_sizes, int n_in,
                              void* d_out, int out_size, void* d_ws, size_t ws_size,
                              hipStream_t stream)
{
    const float* h1    = (const float*)d_in[0];
    const float* h2    = (const float*)d_in[1];
    const float* W1    = (const float*)d_in[2];
    const float* b1    = (const float*)d_in[3];
    const float* gamma = (const float*)d_in[4];
    const float* beta  = (const float*)d_in[5];
    const float* W2    = (const float*)d_in[6];
    const float* b2    = (const float*)d_in[7];
    float* out = (float*)d_out;

    float* ws      = (float*)d_ws;
    float* psumc   = ws;                            // 1024 f
    float* psqc    = psumc + 1024;                  // 1024 f
    unsigned short* W1b = (unsigned short*)(psqc + 1024);   // 98304 us
    unsigned short* W2b = W1b + DHID * DIN;         // 65536 us
    float* Y       = (float*)(W2b + DOUT * DHID);   // 8192*512 = 4M f
    float* psum    = Y + (size_t)N2 * DHID;         // 32*8192 f
    unsigned short* Zb = (unsigned short*)(psum + (size_t)NSPLIT * N2); // 1M us
    // total ~20.3 MB

    hipMemsetAsync(psumc, 0, 2048 * sizeof(float), stream);  // psumc+psqc
    hipMemsetAsync(out, 0, sizeof(float), stream);           // loss accumulator

    convert_w   <<<dim3(160),        256, 0, stream>>>(W1, W2, W1b, W2b);
    gemm1_mfma  <<<dim3(64, 8),      256, 0, stream>>>(h1, h2, W1b, b1, Y, psumc, psqc);
    gemm2_mfma  <<<dim3(512),        256, 0, stream>>>(Y, W2b, psumc, psqc, gamma, beta, b2, Zb, out + 1);
    sim_mfma    <<<dim3(64, NSPLIT), 256, 0, stream>>>(Zb, psum);
    row_finalize<<<dim3(32),         256, 0, stream>>>(Zb, psum, out);
}

// Round 2
// 159.529 us; speedup vs baseline: 1.1769x; 1.1769x over previous
//
#include <hip/hip_runtime.h>

// SimCLR fused pipeline, round 11.
// Change vs r10: sim_mfma reverted to 64 rows/wave (r9 tiling, best measured)
//   + B slice staged in LDS once per block.
//   r9/r10 evidence: per-iter wall ~3000+ cyc with all pipes idle; doubling
//   occupancy (r10) made it WORSE (46->73.6us) because 2x the waves hammered
//   the same lockstep 4KB B-tile in L2 each iter (same-address hotspot ->
//   queueing latency dist-1 prefetch can't cover). Fix: block stages its whole
//   256-col B slice (64KB) into LDS once (bulk, pipelined), XOR-swizzled
//   (row-major [256][256B] would be a 16-way bank conflict on ds_read_b128);
//   the 16-iter MFMA loop then touches LDS only.
// Everything else (gemm1, gemm2, row_finalize, convert_w, psum layout) identical.

#define NB   4096
#define DIN  192
#define DHID 512
#define DOUT 128
#define N2   8192   // 2*NB
#define NSPLIT 32   // sim col-splits; 256 cols per block
#define SIM_ITERS 16

typedef short short8 __attribute__((ext_vector_type(8)));   // 8 bf16 (4 VGPRs)
typedef float floatx4 __attribute__((ext_vector_type(4)));  // MFMA C/D frag

__device__ inline float fast_exp2(float x) {
#if __has_builtin(__builtin_amdgcn_exp2f)
    return __builtin_amdgcn_exp2f(x);
#else
    return exp2f(x);
#endif
}

__device__ inline unsigned short bf16_rne(float x) {
    unsigned int u = __float_as_uint(x);
    return (unsigned short)((u + 0x7fffu + ((u >> 16) & 1u)) >> 16);
}

// ---------------- convert W1, W2 -> bf16 ------------------------------------
__global__ __launch_bounds__(256) void convert_w(
    const float* __restrict__ W1, const float* __restrict__ W2,
    unsigned short* __restrict__ W1b, unsigned short* __restrict__ W2b)
{
    const int NW1 = DHID * DIN / 4;   // 24576 float4
    const int NW2 = DOUT * DHID / 4;  // 16384 float4
    int id = blockIdx.x * 256 + threadIdx.x;
    const float* src; unsigned short* dst; int off;
    if (id < NW1)            { src = W1; dst = W1b; off = id; }
    else if (id < NW1 + NW2) { src = W2; dst = W2b; off = id - NW1; }
    else return;
    float4 x = ((const float4*)src)[off];
    unsigned int p0 = bf16_rne(x.x) | ((unsigned int)bf16_rne(x.y) << 16);
    unsigned int p1 = bf16_rne(x.z) | ((unsigned int)bf16_rne(x.w) << 16);
    ((uint2*)dst)[off] = make_uint2(p0, p1);
}

// ------- GEMM1 (bf16 MFMA): Y = [h1;h2] @ W1^T + b1, fused BN col-sums -----
// grid (64 m-blocks of 128 rows, 8 n-splits of 64 cols), 256 thr (4 waves).
// Wave: 32 rows (2 mt) x 64 cols (4 nt), K=192 (6 kc).
__global__ __launch_bounds__(256) void gemm1_mfma(
    const float* __restrict__ h1, const float* __restrict__ h2,
    const unsigned short* __restrict__ W1b, const float* __restrict__ b1,
    float* __restrict__ Y, float* __restrict__ psumc, float* __restrict__ psqc)
{
    const int t = threadIdx.x;
    const int wave = t >> 6, lane = t & 63;
    const int quad = lane >> 4, l15 = lane & 15;
    const int mb = blockIdx.x;
    const int m0 = mb * 128 + wave * 32;
    const int n0 = blockIdx.y * 64;
    const int v  = (mb >= 32);

    short8 a[2][6];
    #pragma unroll
    for (int mt = 0; mt < 2; ++mt) {
        int row = m0 + mt * 16 + l15;
        const float* hsrc = (row < NB) ? (h1 + (size_t)row * DIN)
                                       : (h2 + (size_t)(row - NB) * DIN);
        #pragma unroll
        for (int kc = 0; kc < 6; ++kc) {
            const float4* p = (const float4*)(hsrc + kc * 32 + quad * 8);
            float4 x0 = p[0], x1 = p[1];
            float xs[8] = {x0.x,x0.y,x0.z,x0.w,x1.x,x1.y,x1.z,x1.w};
            #pragma unroll
            for (int j = 0; j < 8; ++j) a[mt][kc][j] = (short)bf16_rne(xs[j]);
        }
    }

    #pragma unroll
    for (int nt = 0; nt < 4; ++nt) {
        const int col = n0 + nt * 16 + l15;
        const short8* bptr = (const short8*)(W1b + (size_t)col * DIN + quad * 8);
        short8 b[6];
        #pragma unroll
        for (int kc = 0; kc < 6; ++kc) b[kc] = bptr[kc * 4];
        floatx4 acc[2] = {{0.f,0.f,0.f,0.f},{0.f,0.f,0.f,0.f}};
        #pragma unroll
        for (int kc = 0; kc < 6; ++kc)
            #pragma unroll
            for (int mt = 0; mt < 2; ++mt)
                acc[mt] = __builtin_amdgcn_mfma_f32_16x16x32_bf16(a[mt][kc], b[kc], acc[mt], 0,0,0);
        const float bias = b1[col];
        float cs = 0.f, cq = 0.f;
        #pragma unroll
        for (int mt = 0; mt < 2; ++mt)
            #pragma unroll
            for (int reg = 0; reg < 4; ++reg) {
                float y = acc[mt][reg] + bias;
                int row = m0 + mt * 16 + quad * 4 + reg;
                Y[(size_t)row * DHID + col] = y;
                cs += y; cq += y * y;
            }
        cs += __shfl_xor(cs, 16); cs += __shfl_xor(cs, 32);
        cq += __shfl_xor(cq, 16); cq += __shfl_xor(cq, 32);
        if (quad == 0) {
            atomicAdd(psumc + v * DHID + col, cs);
            atomicAdd(psqc  + v * DHID + col, cq);
        }
    }
}

#define ZSCALE 1.6986436f   // sqrt(2*log2(e)); Zb = z*ZSCALE so dot = exp2 arg

// ---- GEMM2 (bf16 MFMA): z = relu(bn(Y)) @ W2^T + b2, L2-norm --------------
// Block: 16 rows x 128 cols, 4 waves (wave w = cols w*32..+31, 2 nt).
// bn-finalize fused in prologue (LDS). 4-wave sq combine via LDS.
// grid 512 x 256 thr.
__global__ __launch_bounds__(256) void gemm2_mfma(
    const float* __restrict__ Y, const unsigned short* __restrict__ W2b,
    const float* __restrict__ psumc, const float* __restrict__ psqc,
    const float* __restrict__ gamma, const float* __restrict__ beta,
    const float* __restrict__ b2,
    unsigned short* __restrict__ Zb, float* __restrict__ outz)
{
    __shared__ float sc_sh[DHID], sh_sh[DHID];
    __shared__ float sq_lds[4][16];
    const int t = threadIdx.x;
    const int wave = t >> 6, lane = t & 63;
    const int quad = lane >> 4, l15 = lane & 15;
    const int mtbase = blockIdx.x * 16;
    const int v = (mtbase >= NB);

    for (int c = t; c < DHID; c += 256) {
        float mean = psumc[v * DHID + c] * (1.0f / NB);
        float var  = psqc [v * DHID + c] * (1.0f / NB) - mean * mean;
        float rstd = rsqrtf(var + 1e-5f);
        float scv = gamma[c] * rstd;
        sc_sh[c] = scv;
        sh_sh[c] = beta[c] - mean * scv;
    }
    __syncthreads();

    const float* yrow = Y + (size_t)(mtbase + l15) * DHID;
    floatx4 acc[2] = {{0.f,0.f,0.f,0.f},{0.f,0.f,0.f,0.f}};
    for (int kc = 0; kc < 16; ++kc) {
        const int k = kc * 32 + quad * 8;
        float4 y0 = *(const float4*)(yrow + k);
        float4 y1 = *(const float4*)(yrow + k + 4);
        float4 s0 = *(const float4*)&sc_sh[k], s1 = *(const float4*)&sc_sh[k + 4];
        float4 h0 = *(const float4*)&sh_sh[k], h1v = *(const float4*)&sh_sh[k + 4];
        float xs[8];
        xs[0] = fmaxf(y0.x * s0.x + h0.x, 0.f);
        xs[1] = fmaxf(y0.y * s0.y + h0.y, 0.f);
        xs[2] = fmaxf(y0.z * s0.z + h0.z, 0.f);
        xs[3] = fmaxf(y0.w * s0.w + h0.w, 0.f);
        xs[4] = fmaxf(y1.x * s1.x + h1v.x, 0.f);
        xs[5] = fmaxf(y1.y * s1.y + h1v.y, 0.f);
        xs[6] = fmaxf(y1.z * s1.z + h1v.z, 0.f);
        xs[7] = fmaxf(y1.w * s1.w + h1v.w, 0.f);
        short8 a;
        #pragma unroll
        for (int j = 0; j < 8; ++j) a[j] = (short)bf16_rne(xs[j]);
        #pragma unroll
        for (int nt = 0; nt < 2; ++nt) {
            const int col = wave * 32 + nt * 16 + l15;
            short8 b = *(const short8*)(W2b + (size_t)col * DHID + k);
            acc[nt] = __builtin_amdgcn_mfma_f32_16x16x32_bf16(a, b, acc[nt], 0,0,0);
        }
    }
    float bias[2];
    #pragma unroll
    for (int nt = 0; nt < 2; ++nt) bias[nt] = b2[wave * 32 + nt * 16 + l15];

    float zv[4][2];
    #pragma unroll
    for (int reg = 0; reg < 4; ++reg) {
        float sq = 0.f;
        #pragma unroll
        for (int nt = 0; nt < 2; ++nt) {
            zv[reg][nt] = acc[nt][reg] + bias[nt];
            sq += zv[reg][nt] * zv[reg][nt];
        }
        sq += __shfl_xor(sq, 1); sq += __shfl_xor(sq, 2);
        sq += __shfl_xor(sq, 4); sq += __shfl_xor(sq, 8);
        if (l15 == 0) sq_lds[wave][quad * 4 + reg] = sq;
    }
    __syncthreads();
    #pragma unroll
    for (int reg = 0; reg < 4; ++reg) {
        float tot = sq_lds[0][quad * 4 + reg] + sq_lds[1][quad * 4 + reg]
                  + sq_lds[2][quad * 4 + reg] + sq_lds[3][quad * 4 + reg];
        float inv = 1.0f / fmaxf(sqrtf(tot), 1e-12f);
        const int row = mtbase + quad * 4 + reg;
        const size_t ob = (size_t)row * DOUT;
        #pragma unroll
        for (int nt = 0; nt < 2; ++nt) {
            const int col = wave * 32 + nt * 16 + l15;
            float z = zv[reg][nt] * inv;
            outz[ob + col] = z;
            Zb[ob + col] = bf16_rne(z * ZSCALE);
        }
    }
}

// ---- sim: psum_row = sum_cols exp2(Zb . Zb^T)  (diag included; subtracted
// in row_finalize). Round-11: r9 tiling (64 rows/wave, a[4][4]) + whole
// 256-col B slice staged in LDS once per block (64KB, XOR-swizzled
// byte ^= (row&7)<<4 so ds_read_b128 is conflict-free). Loop is LDS-only:
// dist-1 LDS ping-pong, 16 MFMA + 16 exp per iter.
// grid (32, NSPLIT) x 256 thr. LDS 64KB -> 2 blocks/CU (8 waves/CU).
__global__ __launch_bounds__(256, 2) void sim_mfma(
    const unsigned short* __restrict__ Zb, float* __restrict__ psum)
{
    __shared__ unsigned char bsh[65536];   // 256 rows x 256 B, swizzled
    const int t = threadIdx.x;
    const int wave = t >> 6, lane = t & 63;
    const int quad = lane >> 4, l15 = lane & 15;
    const int mbase = blockIdx.x * 256 + wave * 64;   // 64 rows per wave
    const int cs = blockIdx.y;                        // 0..NSPLIT-1
    const int cbase = cs * (N2 / NSPLIT);             // 256-col slice

    // ---- stage the whole B slice into LDS (once), swizzled ----
    {
        const uint4* src = (const uint4*)(Zb + (size_t)cbase * DOUT);
        #pragma unroll
        for (int k = 0; k < 16; ++k) {
            int idx = t + k * 256;            // uint4 index 0..4095
            uint4 vv = src[idx];
            int row = idx >> 4;               // slice row 0..255
            int off = (idx & 15) << 4;        // byte offset within row
            *(uint4*)(bsh + row * 256 + (off ^ ((row & 7) << 4))) = vv;
        }
    }

    // A fragments: 64 rows per wave, K=128 (4 kc), kept in regs (r9 layout)
    short8 a[4][4];
    #pragma unroll
    for (int at = 0; at < 4; ++at) {
        const short8* zra = (const short8*)(Zb + (size_t)(mbase + at * 16 + l15) * DOUT + quad * 8);
        #pragma unroll
        for (int kc = 0; kc < 4; ++kc) a[at][kc] = zra[kc * 4];
    }

    float rs[4][4];
    #pragma unroll
    for (int at = 0; at < 4; ++at)
        #pragma unroll
        for (int r = 0; r < 4; ++r) rs[at][r] = 0.f;

    __syncthreads();   // B slice staged

    // swizzled LDS B-frag read: slice row crow, kc chunk, this lane's quad
    auto ldb = [&](int crow, int kc) -> short8 {
        int boff = crow * 256 + ((((kc * 4 + quad) << 4)) ^ ((crow & 7) << 4));
        return *(const short8*)(bsh + boff);
    };

    short8 bcur[4], bnext[4];
    #pragma unroll
    for (int kc = 0; kc < 4; ++kc) bcur[kc] = ldb(l15, kc);

    for (int nt = 0; nt < SIM_ITERS; ++nt) {
        const int crow = ((nt + 1) & (SIM_ITERS - 1)) * 16 + l15;
        #pragma unroll
        for (int kc = 0; kc < 4; ++kc) bnext[kc] = ldb(crow, kc);

        floatx4 acc[4] = {{0.f,0.f,0.f,0.f},{0.f,0.f,0.f,0.f},
                          {0.f,0.f,0.f,0.f},{0.f,0.f,0.f,0.f}};
        #pragma unroll
        for (int kc = 0; kc < 4; ++kc)
            #pragma unroll
            for (int at = 0; at < 4; ++at)
                acc[at] = __builtin_amdgcn_mfma_f32_16x16x32_bf16(a[at][kc], bcur[kc], acc[at], 0, 0, 0);

        #pragma unroll
        for (int at = 0; at < 4; ++at)
            #pragma unroll
            for (int r = 0; r < 4; ++r)
                rs[at][r] += fast_exp2(acc[at][r]);

        #pragma unroll
        for (int kc = 0; kc < 4; ++kc) bcur[kc] = bnext[kc];
    }

    #pragma unroll
    for (int at = 0; at < 4; ++at) {
        const int gi0 = mbase + at * 16 + quad * 4;
        #pragma unroll
        for (int r = 0; r < 4; ++r) {
            float s = rs[at][r];
            s += __shfl_xor(s, 1);
            s += __shfl_xor(s, 2);
            s += __shfl_xor(s, 4);
            s += __shfl_xor(s, 8);
            if (l15 == 0) psum[(size_t)cs * N2 + gi0 + r] = s;
        }
    }
}

// ---- per-row lse - pos, minus diag term; block-reduce -> atomic loss ------
__global__ __launch_bounds__(256) void row_finalize(
    const unsigned short* __restrict__ Zb, const float* __restrict__ psum,
    float* __restrict__ out)
{
    int i = blockIdx.x * 256 + threadIdx.x;
    float s = 0.f;
    #pragma unroll
    for (int cs = 0; cs < NSPLIT; ++cs) s += psum[(size_t)cs * N2 + i];
    int k = i & (NB - 1);
    const uint4* z1 = (const uint4*)(Zb + (size_t)k * DOUT);
    const uint4* z2 = (const uint4*)(Zb + (size_t)(k + NB) * DOUT);
    float d12 = 0.f, d11 = 0.f, d22 = 0.f;
    #pragma unroll
    for (int q = 0; q < 16; ++q) {
        uint4 a = z1[q], bqq = z2[q];
        const unsigned int aw[4] = {a.x, a.y, a.z, a.w};
        const unsigned int bw[4] = {bqq.x, bqq.y, bqq.z, bqq.w};
        #pragma unroll
        for (int c = 0; c < 4; ++c) {
            float alo = __uint_as_float(aw[c] << 16);
            float ahi = __uint_as_float(aw[c] & 0xffff0000u);
            float blo = __uint_as_float(bw[c] << 16);
            float bhi = __uint_as_float(bw[c] & 0xffff0000u);
            d12 += alo * blo + ahi * bhi;
            d11 += alo * alo + ahi * ahi;
            d22 += blo * blo + bhi * bhi;
        }
    }
    float dself = (i < NB) ? d11 : d22;
    // Zb is scaled: dot' = 2*log2(e)*dot => 2*dot = dot'*ln2; diag = exp2(dot')
    float rowval = logf(s - fast_exp2(dself)) - d12 * 0.69314718f;

    float r = rowval;
    r += __shfl_xor(r, 1);  r += __shfl_xor(r, 2);  r += __shfl_xor(r, 4);
    r += __shfl_xor(r, 8);  r += __shfl_xor(r, 16); r += __shfl_xor(r, 32);
    __shared__ float wsr[4];
    int lane = threadIdx.x & 63, w = threadIdx.x >> 6;
    if (lane == 0) wsr[w] = r;
    __syncthreads();
    if (threadIdx.x == 0)
        atomicAdd(out, (wsr[0] + wsr[1] + wsr[2] + wsr[3]) * (1.0f / N2));
}

extern "C" void kernel_launch(void* const* d_in, const int* in_sizes, int n_in,
                              void* d_out, int out_size, void* d_ws, size_t ws_size,
                              hipStream_t stream)
{
    const float* h1    = (const float*)d_in[0];
    const float* h2    = (const float*)d_in[1];
    const float* W1    = (const float*)d_in[2];
    const float* b1    = (const float*)d_in[3];
    const float* gamma = (const float*)d_in[4];
    const float* beta  = (const float*)d_in[5];
    const float* W2    = (const float*)d_in[6];
    const float* b2    = (const float*)d_in[7];
    float* out = (float*)d_out;

    float* ws      = (float*)d_ws;
    float* psumc   = ws;                            // 1024 f
    float* psqc    = psumc + 1024;                  // 1024 f
    unsigned short* W1b = (unsigned short*)(psqc + 1024);   // 98304 us
    unsigned short* W2b = W1b + DHID * DIN;         // 65536 us
    float* Y       = (float*)(W2b + DOUT * DHID);   // 8192*512 = 4M f
    float* psum    = Y + (size_t)N2 * DHID;         // 32*8192 f
    unsigned short* Zb = (unsigned short*)(psum + (size_t)NSPLIT * N2); // 1M us
    // total ~20.3 MB

    hipMemsetAsync(psumc, 0, 2048 * sizeof(float), stream);  // psumc+psqc
    hipMemsetAsync(out, 0, sizeof(float), stream);           // loss accumulator

    convert_w   <<<dim3(160),        256, 0, stream>>>(W1, W2, W1b, W2b);
    gemm1_mfma  <<<dim3(64, 8),      256, 0, stream>>>(h1, h2, W1b, b1, Y, psumc, psqc);
    gemm2_mfma  <<<dim3(512),        256, 0, stream>>>(Y, W2b, psumc, psqc, gamma, beta, b2, Zb, out + 1);
    sim_mfma    <<<dim3(32, NSPLIT), 256, 0, stream>>>(Zb, psum);
    row_finalize<<<dim3(32),         256, 0, stream>>>(Zb, psum, out);
}

// Round 3
// 145.339 us; speedup vs baseline: 1.2918x; 1.0976x over previous
//
#include <hip/hip_runtime.h>

// SimCLR fused pipeline, round 12.
// Change vs r11: sim_mfma register-pressure fix. r11's 64-rows/wave + LDS-B +
//   reg double-buffer demanded ~150 regs, compiler allocated 128 -> ~4 regs
//   spill/filled EVERY iter -> 59.4 MB of scratch HBM writes per dispatch
//   (measured WRITE_SIZE; legit writes are ~1MB) = the whole 50us.
//   Fix: 32 rows/wave (a[2][4]=32 VGPR), B stays LDS-resident (64KB staged
//   once, now 4-bit XOR swizzle so rows r/r+8 don't alias), and NO register
//   double-buffer (ds_read latency hidden by 8 waves/CU TLP + lgkmcnt).
//   Demand ~90 regs -> no spill. grid (64, NSPLIT).
// Everything else (gemm1, gemm2, row_finalize, convert_w, psum layout) identical.

#define NB   4096
#define DIN  192
#define DHID 512
#define DOUT 128
#define N2   8192   // 2*NB
#define NSPLIT 32   // sim col-splits; 256 cols per block
#define SIM_ITERS 16

typedef short short8 __attribute__((ext_vector_type(8)));   // 8 bf16 (4 VGPRs)
typedef float floatx4 __attribute__((ext_vector_type(4)));  // MFMA C/D frag

__device__ inline float fast_exp2(float x) {
#if __has_builtin(__builtin_amdgcn_exp2f)
    return __builtin_amdgcn_exp2f(x);
#else
    return exp2f(x);
#endif
}

__device__ inline unsigned short bf16_rne(float x) {
    unsigned int u = __float_as_uint(x);
    return (unsigned short)((u + 0x7fffu + ((u >> 16) & 1u)) >> 16);
}

// ---------------- convert W1, W2 -> bf16 ------------------------------------
__global__ __launch_bounds__(256) void convert_w(
    const float* __restrict__ W1, const float* __restrict__ W2,
    unsigned short* __restrict__ W1b, unsigned short* __restrict__ W2b)
{
    const int NW1 = DHID * DIN / 4;   // 24576 float4
    const int NW2 = DOUT * DHID / 4;  // 16384 float4
    int id = blockIdx.x * 256 + threadIdx.x;
    const float* src; unsigned short* dst; int off;
    if (id < NW1)            { src = W1; dst = W1b; off = id; }
    else if (id < NW1 + NW2) { src = W2; dst = W2b; off = id - NW1; }
    else return;
    float4 x = ((const float4*)src)[off];
    unsigned int p0 = bf16_rne(x.x) | ((unsigned int)bf16_rne(x.y) << 16);
    unsigned int p1 = bf16_rne(x.z) | ((unsigned int)bf16_rne(x.w) << 16);
    ((uint2*)dst)[off] = make_uint2(p0, p1);
}

// ------- GEMM1 (bf16 MFMA): Y = [h1;h2] @ W1^T + b1, fused BN col-sums -----
// grid (64 m-blocks of 128 rows, 8 n-splits of 64 cols), 256 thr (4 waves).
// Wave: 32 rows (2 mt) x 64 cols (4 nt), K=192 (6 kc).
__global__ __launch_bounds__(256) void gemm1_mfma(
    const float* __restrict__ h1, const float* __restrict__ h2,
    const unsigned short* __restrict__ W1b, const float* __restrict__ b1,
    float* __restrict__ Y, float* __restrict__ psumc, float* __restrict__ psqc)
{
    const int t = threadIdx.x;
    const int wave = t >> 6, lane = t & 63;
    const int quad = lane >> 4, l15 = lane & 15;
    const int mb = blockIdx.x;
    const int m0 = mb * 128 + wave * 32;
    const int n0 = blockIdx.y * 64;
    const int v  = (mb >= 32);

    short8 a[2][6];
    #pragma unroll
    for (int mt = 0; mt < 2; ++mt) {
        int row = m0 + mt * 16 + l15;
        const float* hsrc = (row < NB) ? (h1 + (size_t)row * DIN)
                                       : (h2 + (size_t)(row - NB) * DIN);
        #pragma unroll
        for (int kc = 0; kc < 6; ++kc) {
            const float4* p = (const float4*)(hsrc + kc * 32 + quad * 8);
            float4 x0 = p[0], x1 = p[1];
            float xs[8] = {x0.x,x0.y,x0.z,x0.w,x1.x,x1.y,x1.z,x1.w};
            #pragma unroll
            for (int j = 0; j < 8; ++j) a[mt][kc][j] = (short)bf16_rne(xs[j]);
        }
    }

    #pragma unroll
    for (int nt = 0; nt < 4; ++nt) {
        const int col = n0 + nt * 16 + l15;
        const short8* bptr = (const short8*)(W1b + (size_t)col * DIN + quad * 8);
        short8 b[6];
        #pragma unroll
        for (int kc = 0; kc < 6; ++kc) b[kc] = bptr[kc * 4];
        floatx4 acc[2] = {{0.f,0.f,0.f,0.f},{0.f,0.f,0.f,0.f}};
        #pragma unroll
        for (int kc = 0; kc < 6; ++kc)
            #pragma unroll
            for (int mt = 0; mt < 2; ++mt)
                acc[mt] = __builtin_amdgcn_mfma_f32_16x16x32_bf16(a[mt][kc], b[kc], acc[mt], 0,0,0);
        const float bias = b1[col];
        float cs = 0.f, cq = 0.f;
        #pragma unroll
        for (int mt = 0; mt < 2; ++mt)
            #pragma unroll
            for (int reg = 0; reg < 4; ++reg) {
                float y = acc[mt][reg] + bias;
                int row = m0 + mt * 16 + quad * 4 + reg;
                Y[(size_t)row * DHID + col] = y;
                cs += y; cq += y * y;
            }
        cs += __shfl_xor(cs, 16); cs += __shfl_xor(cs, 32);
        cq += __shfl_xor(cq, 16); cq += __shfl_xor(cq, 32);
        if (quad == 0) {
            atomicAdd(psumc + v * DHID + col, cs);
            atomicAdd(psqc  + v * DHID + col, cq);
        }
    }
}

#define ZSCALE 1.6986436f   // sqrt(2*log2(e)); Zb = z*ZSCALE so dot = exp2 arg

// ---- GEMM2 (bf16 MFMA): z = relu(bn(Y)) @ W2^T + b2, L2-norm --------------
// Block: 16 rows x 128 cols, 4 waves (wave w = cols w*32..+31, 2 nt).
// bn-finalize fused in prologue (LDS). 4-wave sq combine via LDS.
// grid 512 x 256 thr.
__global__ __launch_bounds__(256) void gemm2_mfma(
    const float* __restrict__ Y, const unsigned short* __restrict__ W2b,
    const float* __restrict__ psumc, const float* __restrict__ psqc,
    const float* __restrict__ gamma, const float* __restrict__ beta,
    const float* __restrict__ b2,
    unsigned short* __restrict__ Zb, float* __restrict__ outz)
{
    __shared__ float sc_sh[DHID], sh_sh[DHID];
    __shared__ float sq_lds[4][16];
    const int t = threadIdx.x;
    const int wave = t >> 6, lane = t & 63;
    const int quad = lane >> 4, l15 = lane & 15;
    const int mtbase = blockIdx.x * 16;
    const int v = (mtbase >= NB);

    for (int c = t; c < DHID; c += 256) {
        float mean = psumc[v * DHID + c] * (1.0f / NB);
        float var  = psqc [v * DHID + c] * (1.0f / NB) - mean * mean;
        float rstd = rsqrtf(var + 1e-5f);
        float scv = gamma[c] * rstd;
        sc_sh[c] = scv;
        sh_sh[c] = beta[c] - mean * scv;
    }
    __syncthreads();

    const float* yrow = Y + (size_t)(mtbase + l15) * DHID;
    floatx4 acc[2] = {{0.f,0.f,0.f,0.f},{0.f,0.f,0.f,0.f}};
    for (int kc = 0; kc < 16; ++kc) {
        const int k = kc * 32 + quad * 8;
        float4 y0 = *(const float4*)(yrow + k);
        float4 y1 = *(const float4*)(yrow + k + 4);
        float4 s0 = *(const float4*)&sc_sh[k], s1 = *(const float4*)&sc_sh[k + 4];
        float4 h0 = *(const float4*)&sh_sh[k], h1v = *(const float4*)&sh_sh[k + 4];
        float xs[8];
        xs[0] = fmaxf(y0.x * s0.x + h0.x, 0.f);
        xs[1] = fmaxf(y0.y * s0.y + h0.y, 0.f);
        xs[2] = fmaxf(y0.z * s0.z + h0.z, 0.f);
        xs[3] = fmaxf(y0.w * s0.w + h0.w, 0.f);
        xs[4] = fmaxf(y1.x * s1.x + h1v.x, 0.f);
        xs[5] = fmaxf(y1.y * s1.y + h1v.y, 0.f);
        xs[6] = fmaxf(y1.z * s1.z + h1v.z, 0.f);
        xs[7] = fmaxf(y1.w * s1.w + h1v.w, 0.f);
        short8 a;
        #pragma unroll
        for (int j = 0; j < 8; ++j) a[j] = (short)bf16_rne(xs[j]);
        #pragma unroll
        for (int nt = 0; nt < 2; ++nt) {
            const int col = wave * 32 + nt * 16 + l15;
            short8 b = *(const short8*)(W2b + (size_t)col * DHID + k);
            acc[nt] = __builtin_amdgcn_mfma_f32_16x16x32_bf16(a, b, acc[nt], 0,0,0);
        }
    }
    float bias[2];
    #pragma unroll
    for (int nt = 0; nt < 2; ++nt) bias[nt] = b2[wave * 32 + nt * 16 + l15];

    float zv[4][2];
    #pragma unroll
    for (int reg = 0; reg < 4; ++reg) {
        float sq = 0.f;
        #pragma unroll
        for (int nt = 0; nt < 2; ++nt) {
            zv[reg][nt] = acc[nt][reg] + bias[nt];
            sq += zv[reg][nt] * zv[reg][nt];
        }
        sq += __shfl_xor(sq, 1); sq += __shfl_xor(sq, 2);
        sq += __shfl_xor(sq, 4); sq += __shfl_xor(sq, 8);
        if (l15 == 0) sq_lds[wave][quad * 4 + reg] = sq;
    }
    __syncthreads();
    #pragma unroll
    for (int reg = 0; reg < 4; ++reg) {
        float tot = sq_lds[0][quad * 4 + reg] + sq_lds[1][quad * 4 + reg]
                  + sq_lds[2][quad * 4 + reg] + sq_lds[3][quad * 4 + reg];
        float inv = 1.0f / fmaxf(sqrtf(tot), 1e-12f);
        const int row = mtbase + quad * 4 + reg;
        const size_t ob = (size_t)row * DOUT;
        #pragma unroll
        for (int nt = 0; nt < 2; ++nt) {
            const int col = wave * 32 + nt * 16 + l15;
            float z = zv[reg][nt] * inv;
            outz[ob + col] = z;
            Zb[ob + col] = bf16_rne(z * ZSCALE);
        }
    }
}

// ---- sim: psum_row = sum_cols exp2(Zb . Zb^T)  (diag included; subtracted
// in row_finalize). Round-12: 32 rows/wave (a[2][4], 32 VGPR) + whole 256-col
// B slice LDS-resident (64KB staged once, 4-bit XOR swizzle
// slot ^= row&15 on 16B slots). Loop is LDS-only, NO reg double-buffer:
// per iter 4 ds_read_b128 + 8 MFMA + 8 exp. Reg demand ~90 -> no spill
// (r11 spilled ~4 regs/iter -> 59MB scratch writes = whole kernel time).
// grid (64, NSPLIT) x 256 thr. LDS 64KB -> 2 blocks/CU (8 waves/CU).
__global__ __launch_bounds__(256, 2) void sim_mfma(
    const unsigned short* __restrict__ Zb, float* __restrict__ psum)
{
    __shared__ unsigned char bsh[65536];   // 256 rows x 256 B, swizzled
    const int t = threadIdx.x;
    const int wave = t >> 6, lane = t & 63;
    const int quad = lane >> 4, l15 = lane & 15;
    const int mbase = blockIdx.x * 128 + wave * 32;   // 32 rows per wave
    const int cs = blockIdx.y;                        // 0..NSPLIT-1
    const int cbase = cs * (N2 / NSPLIT);             // 256-col slice

    // ---- stage the whole B slice into LDS (once), swizzled ----
    {
        const uint4* src = (const uint4*)(Zb + (size_t)cbase * DOUT);
        #pragma unroll
        for (int k = 0; k < 16; ++k) {
            int idx = t + k * 256;            // uint4 index 0..4095
            uint4 vv = src[idx];
            int row  = idx >> 4;              // slice row 0..255
            int slot = idx & 15;              // 16B slot within row
            *(uint4*)(bsh + row * 256 + ((slot ^ (row & 15)) << 4)) = vv;
        }
    }

    // A fragments: 32 rows per wave, K=128 (4 kc), kept in regs
    short8 a[2][4];
    #pragma unroll
    for (int at = 0; at < 2; ++at) {
        const short8* zra = (const short8*)(Zb + (size_t)(mbase + at * 16 + l15) * DOUT + quad * 8);
        #pragma unroll
        for (int kc = 0; kc < 4; ++kc) a[at][kc] = zra[kc * 4];
    }

    float rs[2][4];
    #pragma unroll
    for (int at = 0; at < 2; ++at)
        #pragma unroll
        for (int r = 0; r < 4; ++r) rs[at][r] = 0.f;

    __syncthreads();   // B slice staged

    #pragma unroll 1
    for (int nt = 0; nt < SIM_ITERS; ++nt) {
        const int crow = nt * 16 + l15;
        short8 b[4];
        #pragma unroll
        for (int kc = 0; kc < 4; ++kc) {
            int slot = kc * 4 + quad;
            int boff = crow * 256 + ((slot ^ (crow & 15)) << 4);
            b[kc] = *(const short8*)(bsh + boff);
        }

        floatx4 acc[2] = {{0.f,0.f,0.f,0.f},{0.f,0.f,0.f,0.f}};
        #pragma unroll
        for (int kc = 0; kc < 4; ++kc)
            #pragma unroll
            for (int at = 0; at < 2; ++at)
                acc[at] = __builtin_amdgcn_mfma_f32_16x16x32_bf16(a[at][kc], b[kc], acc[at], 0, 0, 0);

        #pragma unroll
        for (int at = 0; at < 2; ++at)
            #pragma unroll
            for (int r = 0; r < 4; ++r)
                rs[at][r] += fast_exp2(acc[at][r]);
    }

    #pragma unroll
    for (int at = 0; at < 2; ++at) {
        const int gi0 = mbase + at * 16 + quad * 4;
        #pragma unroll
        for (int r = 0; r < 4; ++r) {
            float s = rs[at][r];
            s += __shfl_xor(s, 1);
            s += __shfl_xor(s, 2);
            s += __shfl_xor(s, 4);
            s += __shfl_xor(s, 8);
            if (l15 == 0) psum[(size_t)cs * N2 + gi0 + r] = s;
        }
    }
}

// ---- per-row lse - pos, minus diag term; block-reduce -> atomic loss ------
__global__ __launch_bounds__(256) void row_finalize(
    const unsigned short* __restrict__ Zb, const float* __restrict__ psum,
    float* __restrict__ out)
{
    int i = blockIdx.x * 256 + threadIdx.x;
    float s = 0.f;
    #pragma unroll
    for (int cs = 0; cs < NSPLIT; ++cs) s += psum[(size_t)cs * N2 + i];
    int k = i & (NB - 1);
    const uint4* z1 = (const uint4*)(Zb + (size_t)k * DOUT);
    const uint4* z2 = (const uint4*)(Zb + (size_t)(k + NB) * DOUT);
    float d12 = 0.f, d11 = 0.f, d22 = 0.f;
    #pragma unroll
    for (int q = 0; q < 16; ++q) {
        uint4 a = z1[q], bqq = z2[q];
        const unsigned int aw[4] = {a.x, a.y, a.z, a.w};
        const unsigned int bw[4] = {bqq.x, bqq.y, bqq.z, bqq.w};
        #pragma unroll
        for (int c = 0; c < 4; ++c) {
            float alo = __uint_as_float(aw[c] << 16);
            float ahi = __uint_as_float(aw[c] & 0xffff0000u);
            float blo = __uint_as_float(bw[c] << 16);
            float bhi = __uint_as_float(bw[c] & 0xffff0000u);
            d12 += alo * blo + ahi * bhi;
            d11 += alo * alo + ahi * ahi;
            d22 += blo * blo + bhi * bhi;
        }
    }
    float dself = (i < NB) ? d11 : d22;
    // Zb is scaled: dot' = 2*log2(e)*dot => 2*dot = dot'*ln2; diag = exp2(dot')
    float rowval = logf(s - fast_exp2(dself)) - d12 * 0.69314718f;

    float r = rowval;
    r += __shfl_xor(r, 1);  r += __shfl_xor(r, 2);  r += __shfl_xor(r, 4);
    r += __shfl_xor(r, 8);  r += __shfl_xor(r, 16); r += __shfl_xor(r, 32);
    __shared__ float wsr[4];
    int lane = threadIdx.x & 63, w = threadIdx.x >> 6;
    if (lane == 0) wsr[w] = r;
    __syncthreads();
    if (threadIdx.x == 0)
        atomicAdd(out, (wsr[0] + wsr[1] + wsr[2] + wsr[3]) * (1.0f / N2));
}

extern "C" void kernel_launch(void* const* d_in, const int* in_sizes, int n_in,
                              void* d_out, int out_size, void* d_ws, size_t ws_size,
                              hipStream_t stream)
{
    const float* h1    = (const float*)d_in[0];
    const float* h2    = (const float*)d_in[1];
    const float* W1    = (const float*)d_in[2];
    const float* b1    = (const float*)d_in[3];
    const float* gamma = (const float*)d_in[4];
    const float* beta  = (const float*)d_in[5];
    const float* W2    = (const float*)d_in[6];
    const float* b2    = (const float*)d_in[7];
    float* out = (float*)d_out;

    float* ws      = (float*)d_ws;
    float* psumc   = ws;                            // 1024 f
    float* psqc    = psumc + 1024;                  // 1024 f
    unsigned short* W1b = (unsigned short*)(psqc + 1024);   // 98304 us
    unsigned short* W2b = W1b + DHID * DIN;         // 65536 us
    float* Y       = (float*)(W2b + DOUT * DHID);   // 8192*512 = 4M f
    float* psum    = Y + (size_t)N2 * DHID;         // 32*8192 f
    unsigned short* Zb = (unsigned short*)(psum + (size_t)NSPLIT * N2); // 1M us
    // total ~20.3 MB

    hipMemsetAsync(psumc, 0, 2048 * sizeof(float), stream);  // psumc+psqc
    hipMemsetAsync(out, 0, sizeof(float), stream);           // loss accumulator

    convert_w   <<<dim3(160),        256, 0, stream>>>(W1, W2, W1b, W2b);
    gemm1_mfma  <<<dim3(64, 8),      256, 0, stream>>>(h1, h2, W1b, b1, Y, psumc, psqc);
    gemm2_mfma  <<<dim3(512),        256, 0, stream>>>(Y, W2b, psumc, psqc, gamma, beta, b2, Zb, out + 1);
    sim_mfma    <<<dim3(64, NSPLIT), 256, 0, stream>>>(Zb, psum);
    row_finalize<<<dim3(32),         256, 0, stream>>>(Zb, psum, out);
}